// Round 6
// baseline (2106.201 us; speedup 1.0000x reference)
//
#include <hip/hip_runtime.h>
#include <math.h>

#define NN 2048
#define MM 16384
#define NB 512          // blocks in the fused iteration kernel

typedef __attribute__((ext_vector_type(4))) float f32x4;
typedef __attribute__((ext_vector_type(2))) float f32x2;

struct Bar { unsigned cntA; unsigned cntB; int flagA; int done; };

// ===========================================================================
// Sinkhorn, fp8(e4m3) kernel matrix, ONE fused kernel per iteration.
//   K8[i][j] = KT8[j][i] = fp8(exp(-10*D[i][j]))      (one-time prep)
//   phase A: f[j] = -log(dot(KT8[j], w)+eps)/1.1 ; v[j] = pd[j]*exp(f[j])
//   (in-kernel device barrier, epoch = iteration index)
//   phase B: g[i] = -log(dot(K8[i],  v)+eps)     ; w[i] = tm[i]*exp(g[i])
//   last phase-B block reduces |dg| deterministically and sets done.
// ===========================================================================

__global__ __launch_bounds__(256)
void k_prep(const float* __restrict__ D,
            unsigned char* __restrict__ K8,
            unsigned char* __restrict__ KT8,
            const float* __restrict__ tm,
            float* __restrict__ g, float* __restrict__ w,
            Bar* __restrict__ bar) {
    if (blockIdx.x == 0 && blockIdx.y == 0) {       // folded init
        for (int i = threadIdx.x; i < NN; i += 256) { g[i] = 0.0f; w[i] = tm[i]; }
        if (threadIdx.x == 0) {
            bar->cntA = 0u; bar->cntB = 0u; bar->flagA = 0; bar->done = 0;
        }
    }
    __shared__ unsigned char t[64][72];
    const int j0 = blockIdx.x * 64, i0 = blockIdx.y * 64;
    const int tid = threadIdx.x;
    const int r = tid >> 4, c4 = tid & 15;
#pragma unroll
    for (int rp = 0; rp < 4; ++rp) {
        const int row = i0 + rp * 16 + r;
        f32x4 d = *(const f32x4*)(D + (size_t)row * MM + j0 + c4 * 4);
        float e0 = __expf(-10.0f * d[0]);
        float e1 = __expf(-10.0f * d[1]);
        float e2 = __expf(-10.0f * d[2]);
        float e3 = __expf(-10.0f * d[3]);
        int p = __builtin_amdgcn_cvt_pk_fp8_f32(e0, e1, 0, false);
        p = __builtin_amdgcn_cvt_pk_fp8_f32(e2, e3, p, true);
        *(unsigned*)(K8 + (size_t)row * MM + j0 + c4 * 4) = (unsigned)p;
        t[c4 * 4 + 0][rp * 16 + r] = (unsigned char)(p & 0xff);
        t[c4 * 4 + 1][rp * 16 + r] = (unsigned char)((p >> 8) & 0xff);
        t[c4 * 4 + 2][rp * 16 + r] = (unsigned char)((p >> 16) & 0xff);
        t[c4 * 4 + 3][rp * 16 + r] = (unsigned char)((p >> 24) & 0xff);
    }
    __syncthreads();
#pragma unroll
    for (int p2 = 0; p2 < 4; ++p2) {
        const int item = p2 * 256 + tid;
        const int jl = item >> 4, iw = item & 15;
        unsigned val = *(const unsigned*)&t[jl][iw * 4];
        *(unsigned*)(KT8 + (size_t)(j0 + jl) * NN + i0 + iw * 4) = val;
    }
}

// ---- fused per-iteration kernel: NB blocks x 256 thr ----------------------
__global__ __launch_bounds__(256, 2)      // VGPR<=256 -> >=2 blocks/CU -> all
void k_iter(const unsigned char* __restrict__ K8,     // NB blocks co-resident
            const unsigned char* __restrict__ KT8,
            const float* __restrict__ pd, const float* __restrict__ tm,
            float* __restrict__ f, float* __restrict__ v,
            float* __restrict__ g, float* __restrict__ w,
            float* __restrict__ diffpart, Bar* __restrict__ bar, int it) {
    if (bar->done) return;
    const int tid = threadIdx.x, lane = tid & 63, wid = tid >> 6;

    // ================= phase A: 32 KT rows per block (8 per wave) ==========
    {
        float wr[2][16];                       // register-cached slice of w
#pragma unroll
        for (int k = 0; k < 2; ++k) {
            const f32x4* p = (const f32x4*)(w + k * 1024 + lane * 16);
#pragma unroll
            for (int q = 0; q < 4; ++q) {
                f32x4 a = p[q];
                wr[k][q * 4 + 0] = a[0]; wr[k][q * 4 + 1] = a[1];
                wr[k][q * 4 + 2] = a[2]; wr[k][q * 4 + 3] = a[3];
            }
        }
        const int jbase = blockIdx.x * 32 + wid * 8;
#pragma unroll
        for (int r = 0; r < 8; ++r) {
            const int j = jbase + r;
            const unsigned char* row = KT8 + (size_t)j * NN;
            float acc = 0.0f;
#pragma unroll
            for (int k = 0; k < 2; ++k) {
                uint4 qw = *(const uint4*)(row + k * 1024 + lane * 16);
                unsigned u[4] = {qw.x, qw.y, qw.z, qw.w};
#pragma unroll
                for (int c = 0; c < 4; ++c) {
                    f32x2 lo = __builtin_amdgcn_cvt_pk_f32_fp8(u[c], false);
                    f32x2 hi = __builtin_amdgcn_cvt_pk_f32_fp8(u[c], true);
                    acc = fmaf(lo[0], wr[k][c * 4 + 0], acc);
                    acc = fmaf(lo[1], wr[k][c * 4 + 1], acc);
                    acc = fmaf(hi[0], wr[k][c * 4 + 2], acc);
                    acc = fmaf(hi[1], wr[k][c * 4 + 3], acc);
                }
            }
#pragma unroll
            for (int s = 32; s; s >>= 1) acc += __shfl_xor(acc, s, 64);
            if (lane == 0) {
                float fj = -__logf(acc + 1e-7f) * (1.0f / 1.1f);
                f[j] = fj;
                v[j] = pd[j] * __expf(fj);
            }
        }
    }

    // ================= device barrier (epoch = it) =========================
    __syncthreads();                           // all block stores drained
    if (tid == 0) {
        __threadfence();                       // flush our v-writes to device
        unsigned old = atomicAdd(&bar->cntA, 1u);
        if (old == (unsigned)(NB * it + NB - 1))
            __hip_atomic_store(&bar->flagA, it + 1, __ATOMIC_RELEASE,
                               __HIP_MEMORY_SCOPE_AGENT);
        while (__hip_atomic_load(&bar->flagA, __ATOMIC_ACQUIRE,
                                 __HIP_MEMORY_SCOPE_AGENT) < it + 1)
            __builtin_amdgcn_s_sleep(1);
        __threadfence();                       // invalidate stale lines
    }
    __syncthreads();                           // release whole block

    // ================= phase B: 4 K rows per block (round-4 body) ==========
    const int i0 = blockIdx.x * 4;
    float vr[4][16];                           // whole v register-cached
#pragma unroll
    for (int k = 0; k < 4; ++k) {
        const f32x4* p = (const f32x4*)(v + k * 4096 + tid * 16);
#pragma unroll
        for (int q = 0; q < 4; ++q) {
            f32x4 a = p[q];
            vr[k][q * 4 + 0] = a[0]; vr[k][q * 4 + 1] = a[1];
            vr[k][q * 4 + 2] = a[2]; vr[k][q * 4 + 3] = a[3];
        }
    }
    f32x4 accv = {0.f, 0.f, 0.f, 0.f};
#pragma unroll
    for (int r = 0; r < 4; ++r) {
        const unsigned char* row = K8 + (size_t)(i0 + r) * MM;
        float acc = 0.0f;
#pragma unroll
        for (int k = 0; k < 4; ++k) {
            uint4 qw = *(const uint4*)(row + k * 4096 + tid * 16);
            unsigned u[4] = {qw.x, qw.y, qw.z, qw.w};
#pragma unroll
            for (int c = 0; c < 4; ++c) {
                f32x2 lo = __builtin_amdgcn_cvt_pk_f32_fp8(u[c], false);
                f32x2 hi = __builtin_amdgcn_cvt_pk_f32_fp8(u[c], true);
                acc = fmaf(lo[0], vr[k][c * 4 + 0], acc);
                acc = fmaf(lo[1], vr[k][c * 4 + 1], acc);
                acc = fmaf(hi[0], vr[k][c * 4 + 2], acc);
                acc = fmaf(hi[1], vr[k][c * 4 + 3], acc);
            }
        }
        accv[r] = acc;
    }
    __shared__ f32x4 red[256];
    red[tid] = accv;
    __syncthreads();
    for (int s = 128; s; s >>= 1) {
        if (tid < s) red[tid] += red[tid + s];
        __syncthreads();
    }
    __shared__ bool last;
    if (tid == 0) {
        f32x4 sv = red[0];
        float dp = 0.0f;
#pragma unroll
        for (int r = 0; r < 4; ++r) {
            float gn = -__logf(sv[r] + 1e-7f);
            dp += fabsf(gn - g[i0 + r]);
            g[i0 + r] = gn;
            w[i0 + r] = tm[i0 + r] * __expf(gn);
        }
        diffpart[blockIdx.x] = dp;
        __threadfence();                       // release diffpart/g/w
        unsigned old = atomicAdd(&bar->cntB, 1u);
        last = (old == (unsigned)(NB * it + NB - 1));
    }
    __syncthreads();

    if (last) {                                // deterministic fixed-order check
        __threadfence();                       // acquire others' writes
        __shared__ float redc[256];
        redc[tid] = diffpart[tid] + diffpart[tid + 256];
        __syncthreads();
        for (int s2 = 128; s2; s2 >>= 1) {
            if (tid < s2) redc[tid] += redc[tid + s2];
            __syncthreads();
        }
        if (tid == 0 && 0.1f * (redc[0] / (float)NN) < 5e-4f)
            bar->done = 1;
    }
}

__global__ void k_out(const float* __restrict__ f,
                      const float* __restrict__ g,
                      float* __restrict__ out) {
    const int idx = blockIdx.x * 256 + threadIdx.x;
    if (idx < MM) {
        out[idx] = 1.0f - __expf(-0.1f * f[idx]);
    } else if (idx < MM + NN) {
        out[idx] = 0.1f * g[idx - MM];
    }
}

// ===========================================================================
// Legacy fallback (round-1 proven fp32 pipeline) if ws can't hold K8 + KT8.
// ===========================================================================
__global__ void k_f_partial(const float* __restrict__ dis,
                            const float* __restrict__ tm,
                            const float* __restrict__ g,
                            float* __restrict__ s_f,
                            const int* __restrict__ done) {
    if (*done) return;
    const int j  = blockIdx.x * 256 + threadIdx.x;
    const int i0 = blockIdx.y * (NN / 8);
    const float* p = dis + (size_t)i0 * MM + j;
    float acc = 0.f;
#pragma unroll 4
    for (int i = 0; i < NN / 8; ++i) {
        float d = p[(size_t)i * MM];
        float e = __expf(fmaf(d, -10.0f, g[i0 + i]));
        acc = fmaf(tm[i0 + i], e, acc);
    }
    atomicAdd(&s_f[j], acc);
}

__global__ void k_f_final(float* __restrict__ f, float* __restrict__ s_f,
                          const int* __restrict__ done) {
    if (*done) return;
    const int j = blockIdx.x * 256 + threadIdx.x;
    f[j] = -__logf(s_f[j] + 1e-7f) * (1.0f / 1.1f);
    s_f[j] = 0.f;
}

__global__ void k_g_row(const float* __restrict__ dis,
                        const float* __restrict__ pd,
                        const float* __restrict__ f,
                        float* __restrict__ g,
                        float* __restrict__ diff_acc,
                        const int* __restrict__ done) {
    if (*done) return;
    const int i = blockIdx.x;
    const float* p = dis + (size_t)i * MM;
    float acc = 0.f;
#pragma unroll 4
    for (int j = threadIdx.x; j < MM; j += 256) {
        float e = __expf(fmaf(p[j], -10.0f, f[j]));
        acc = fmaf(pd[j], e, acc);
    }
    __shared__ float red[256];
    red[threadIdx.x] = acc;
    __syncthreads();
    for (int s = 128; s > 0; s >>= 1) {
        if (threadIdx.x < s) red[threadIdx.x] += red[threadIdx.x + s];
        __syncthreads();
    }
    if (threadIdx.x == 0) {
        float gn = -__logf(red[0] + 1e-7f);
        atomicAdd(diff_acc, fabsf(gn - g[i]));
        g[i] = gn;
    }
}

__global__ void k_check(float* __restrict__ diff_acc, int* __restrict__ done) {
    if (!*done) {
        float diff = 0.1f * (*diff_acc / (float)NN);
        if (diff < 5e-4f) *done = 1;
    }
    *diff_acc = 0.f;
}

// ===========================================================================
extern "C" void kernel_launch(void* const* d_in, const int* in_sizes, int n_in,
                              void* d_out, int out_size, void* d_ws, size_t ws_size,
                              hipStream_t stream) {
    const float* dis = (const float*)d_in[0];   // (NN, MM) fp32
    const float* pd  = (const float*)d_in[1];   // (MM,)
    const float* tm  = (const float*)d_in[2];   // (NN,)
    float* out = (float*)d_out;

    const size_t kBytes = (size_t)NN * MM;      // 32 MiB each (fp8)
    const size_t need   = 2 * kBytes
                        + (size_t)(2 * MM + 2 * NN + NB) * sizeof(float) + 64;

    if (ws_size >= need) {
        unsigned char* K8  = (unsigned char*)d_ws;
        unsigned char* KT8 = (unsigned char*)d_ws + kBytes;
        float* fbuf     = (float*)((char*)d_ws + 2 * kBytes);
        float* vbuf     = fbuf + MM;
        float* gbuf     = vbuf + MM;
        float* wbuf     = gbuf + NN;
        float* diffpart = wbuf + NN;            // NB floats
        Bar*   bar      = (Bar*)(diffpart + NB);

        k_prep<<<dim3(MM / 64, NN / 64), 256, 0, stream>>>(dis, K8, KT8,
                                                           tm, gbuf, wbuf, bar);
        for (int it = 0; it < 100; ++it) {
            k_iter<<<NB, 256, 0, stream>>>(K8, KT8, pd, tm, fbuf, vbuf,
                                           gbuf, wbuf, diffpart, bar, it);
        }
        k_out<<<(MM + NN + 255) / 256, 256, 0, stream>>>(fbuf, gbuf, out);
    } else {
        // ---------------- legacy fallback ----------------
        float* g        = (float*)d_ws;
        float* f        = g + NN;
        float* s_f      = f + MM;
        float* diff_acc = s_f + MM;
        int*   done     = (int*)(diff_acc + 1);

        hipMemsetAsync(d_ws, 0, (size_t)(NN + 2 * MM + 2) * sizeof(float), stream);

        dim3 gridF(MM / 256, 8);
        for (int it = 0; it < 100; ++it) {
            k_f_partial<<<gridF, 256, 0, stream>>>(dis, tm, g, s_f, done);
            k_f_final<<<MM / 256, 256, 0, stream>>>(f, s_f, done);
            k_g_row<<<NN, 256, 0, stream>>>(dis, pd, f, g, diff_acc, done);
            k_check<<<1, 1, 0, stream>>>(diff_acc, done);
        }
        k_out<<<(MM + NN + 255) / 256, 256, 0, stream>>>(f, g, out);
    }
}

// Round 7
// 904.458 us; speedup vs baseline: 2.3287x; 2.3287x over previous
//
#include <hip/hip_runtime.h>
#include <math.h>

#define NN 2048
#define MM 16384

typedef __attribute__((ext_vector_type(4))) float f32x4;
typedef __attribute__((ext_vector_type(2))) float f32x2;

// ===========================================================================
// Sinkhorn with precomputed fp8(e4m3) kernel matrix (OCP, gfx950 native).
// Round-7 = round-4 proven structure (909.6 us), k_init folded into k_prep.
//   K8[i][j] = KT8[j][i] = fp8(exp(-10*D[i][j]))      (one-time prep)
//   phase A: f[j] = -log(dot(KT8[j], w)+eps)/1.1 ; v[j] = pd[j]*exp(f[j])
//   phase B: g[i] = -log(dot(K8[i],  v)+eps)     ; w[i] = tm[i]*exp(g[i])
//            + per-block |dg| partials; last block reduces deterministically
//            and sets done (freeze), emulating the torch break.
// Rationale locked by rounds 5/6: launch edges are the cheapest grid barrier
// (device-scope barrier invalidates per-XCD L2 -> 82us iters); (256,2) beats
// (256,4) (extra waves only add v-broadcast traffic + spills).
// ===========================================================================

__global__ __launch_bounds__(256)
void k_prep(const float* __restrict__ D,
            unsigned char* __restrict__ K8,
            unsigned char* __restrict__ KT8,
            const float* __restrict__ tm,
            float* __restrict__ g, float* __restrict__ w,
            unsigned* __restrict__ counter, int* __restrict__ done) {
    if (blockIdx.x == 0 && blockIdx.y == 0) {       // folded init
        for (int i = threadIdx.x; i < NN; i += 256) { g[i] = 0.0f; w[i] = tm[i]; }
        if (threadIdx.x == 0) { *counter = 0u; *done = 0; }
    }
    __shared__ unsigned char t[64][72];     // 72 % 4 == 0 -> aligned u32 reads
    const int j0 = blockIdx.x * 64, i0 = blockIdx.y * 64;
    const int tid = threadIdx.x;
    const int r = tid >> 4, c4 = tid & 15;  // 16 rows x 16 col-quads per pass
#pragma unroll
    for (int rp = 0; rp < 4; ++rp) {
        const int row = i0 + rp * 16 + r;
        f32x4 d = *(const f32x4*)(D + (size_t)row * MM + j0 + c4 * 4);
        float e0 = __expf(-10.0f * d[0]);
        float e1 = __expf(-10.0f * d[1]);
        float e2 = __expf(-10.0f * d[2]);
        float e3 = __expf(-10.0f * d[3]);
        int p = __builtin_amdgcn_cvt_pk_fp8_f32(e0, e1, 0, false);
        p = __builtin_amdgcn_cvt_pk_fp8_f32(e2, e3, p, true);
        *(unsigned*)(K8 + (size_t)row * MM + j0 + c4 * 4) = (unsigned)p;
        t[c4 * 4 + 0][rp * 16 + r] = (unsigned char)(p & 0xff);
        t[c4 * 4 + 1][rp * 16 + r] = (unsigned char)((p >> 8) & 0xff);
        t[c4 * 4 + 2][rp * 16 + r] = (unsigned char)((p >> 16) & 0xff);
        t[c4 * 4 + 3][rp * 16 + r] = (unsigned char)((p >> 24) & 0xff);
    }
    __syncthreads();
#pragma unroll
    for (int p2 = 0; p2 < 4; ++p2) {
        const int item = p2 * 256 + tid;          // 64 rows x 16 words
        const int jl = item >> 4, iw = item & 15;
        unsigned val = *(const unsigned*)&t[jl][iw * 4];
        *(unsigned*)(KT8 + (size_t)(j0 + jl) * NN + i0 + iw * 4) = val;
    }
}

// ---- phase A: 1024 blocks x 256 thr; each wave handles 4 KT rows ----------
__global__ __launch_bounds__(256, 2)
void k_phaseA(const unsigned char* __restrict__ KT8, const float* __restrict__ pd,
              const float* __restrict__ w, float* __restrict__ f,
              float* __restrict__ v, const int* __restrict__ done) {
    if (*done) return;
    const int tid = threadIdx.x, lane = tid & 63, wid = tid >> 6;

    float wr[2][16];                         // register-cached slice of w
#pragma unroll
    for (int k = 0; k < 2; ++k) {
        const f32x4* p = (const f32x4*)(w + k * 1024 + lane * 16);
#pragma unroll
        for (int q = 0; q < 4; ++q) {
            f32x4 a = p[q];
            wr[k][q * 4 + 0] = a[0]; wr[k][q * 4 + 1] = a[1];
            wr[k][q * 4 + 2] = a[2]; wr[k][q * 4 + 3] = a[3];
        }
    }
    const int jbase = blockIdx.x * 16 + wid * 4;
#pragma unroll
    for (int r = 0; r < 4; ++r) {
        const int j = jbase + r;
        const unsigned char* row = KT8 + (size_t)j * NN;
        float acc = 0.0f;
#pragma unroll
        for (int k = 0; k < 2; ++k) {
            uint4 qw = *(const uint4*)(row + k * 1024 + lane * 16);
            unsigned u[4] = {qw.x, qw.y, qw.z, qw.w};
#pragma unroll
            for (int c = 0; c < 4; ++c) {
                f32x2 lo = __builtin_amdgcn_cvt_pk_f32_fp8(u[c], false);
                f32x2 hi = __builtin_amdgcn_cvt_pk_f32_fp8(u[c], true);
                acc = fmaf(lo[0], wr[k][c * 4 + 0], acc);
                acc = fmaf(lo[1], wr[k][c * 4 + 1], acc);
                acc = fmaf(hi[0], wr[k][c * 4 + 2], acc);
                acc = fmaf(hi[1], wr[k][c * 4 + 3], acc);
            }
        }
#pragma unroll
        for (int s = 32; s; s >>= 1) acc += __shfl_xor(acc, s, 64);
        if (lane == 0) {
            float fj = -__logf(acc + 1e-7f) * (1.0f / 1.1f);
            f[j] = fj;
            v[j] = pd[j] * __expf(fj);
        }
    }
}

// ---- phase B: 512 blocks x 256 thr; block handles 4 K rows, v in regs -----
__global__ __launch_bounds__(256, 2)
void k_phaseB(const unsigned char* __restrict__ K8, const float* __restrict__ tm,
              const float* __restrict__ v, float* __restrict__ g,
              float* __restrict__ w, float* __restrict__ diffpart,
              unsigned* __restrict__ counter, int* __restrict__ done) {
    if (*done) return;
    const int tid = threadIdx.x;
    const int i0  = blockIdx.x * 4;

    float vr[4][16];                         // whole v register-cached (block)
#pragma unroll
    for (int k = 0; k < 4; ++k) {
        const f32x4* p = (const f32x4*)(v + k * 4096 + tid * 16);
#pragma unroll
        for (int q = 0; q < 4; ++q) {
            f32x4 a = p[q];
            vr[k][q * 4 + 0] = a[0]; vr[k][q * 4 + 1] = a[1];
            vr[k][q * 4 + 2] = a[2]; vr[k][q * 4 + 3] = a[3];
        }
    }
    f32x4 accv = {0.f, 0.f, 0.f, 0.f};
#pragma unroll
    for (int r = 0; r < 4; ++r) {
        const unsigned char* row = K8 + (size_t)(i0 + r) * MM;
        float acc = 0.0f;
#pragma unroll
        for (int k = 0; k < 4; ++k) {
            uint4 qw = *(const uint4*)(row + k * 4096 + tid * 16);
            unsigned u[4] = {qw.x, qw.y, qw.z, qw.w};
#pragma unroll
            for (int c = 0; c < 4; ++c) {
                f32x2 lo = __builtin_amdgcn_cvt_pk_f32_fp8(u[c], false);
                f32x2 hi = __builtin_amdgcn_cvt_pk_f32_fp8(u[c], true);
                acc = fmaf(lo[0], vr[k][c * 4 + 0], acc);
                acc = fmaf(lo[1], vr[k][c * 4 + 1], acc);
                acc = fmaf(hi[0], vr[k][c * 4 + 2], acc);
                acc = fmaf(hi[1], vr[k][c * 4 + 3], acc);
            }
        }
        accv[r] = acc;
    }
    __shared__ f32x4 red[256];
    red[tid] = accv;
    __syncthreads();
    for (int s = 128; s; s >>= 1) {
        if (tid < s) red[tid] += red[tid + s];
        __syncthreads();
    }
    __shared__ bool last;
    if (tid == 0) {
        f32x4 sv = red[0];
        float dp = 0.0f;
#pragma unroll
        for (int r = 0; r < 4; ++r) {
            float gn = -__logf(sv[r] + 1e-7f);
            dp += fabsf(gn - g[i0 + r]);
            g[i0 + r] = gn;
            w[i0 + r] = tm[i0 + r] * __expf(gn);
        }
        diffpart[blockIdx.x] = dp;
        __threadfence();                      // release diffpart/g/w
        unsigned old = atomicAdd(counter, 1u);
        last = (old == gridDim.x - 1);
    }
    __syncthreads();

    if (last) {                               // deterministic fixed-order check
        __threadfence();                      // acquire others' writes
        __shared__ float red1[256];
        red1[tid] = diffpart[tid] + diffpart[tid + 256];
        __syncthreads();
        for (int s2 = 128; s2; s2 >>= 1) {
            if (tid < s2) red1[tid] += red1[tid + s2];
            __syncthreads();
        }
        if (tid == 0) {
            if (0.1f * (red1[0] / (float)NN) < 5e-4f) *done = 1;
            *counter = 0u;                    // re-arm for next iteration
        }
    }
}

__global__ void k_out(const float* __restrict__ f,
                      const float* __restrict__ g,
                      float* __restrict__ out) {
    const int idx = blockIdx.x * 256 + threadIdx.x;
    if (idx < MM) {
        out[idx] = 1.0f - __expf(-0.1f * f[idx]);
    } else if (idx < MM + NN) {
        out[idx] = 0.1f * g[idx - MM];
    }
}

// ===========================================================================
// Legacy fallback (round-1 proven fp32 pipeline) if ws can't hold K8 + KT8.
// ===========================================================================
__global__ void k_f_partial(const float* __restrict__ dis,
                            const float* __restrict__ tm,
                            const float* __restrict__ g,
                            float* __restrict__ s_f,
                            const int* __restrict__ done) {
    if (*done) return;
    const int j  = blockIdx.x * 256 + threadIdx.x;
    const int i0 = blockIdx.y * (NN / 8);
    const float* p = dis + (size_t)i0 * MM + j;
    float acc = 0.f;
#pragma unroll 4
    for (int i = 0; i < NN / 8; ++i) {
        float d = p[(size_t)i * MM];
        float e = __expf(fmaf(d, -10.0f, g[i0 + i]));
        acc = fmaf(tm[i0 + i], e, acc);
    }
    atomicAdd(&s_f[j], acc);
}

__global__ void k_f_final(float* __restrict__ f, float* __restrict__ s_f,
                          const int* __restrict__ done) {
    if (*done) return;
    const int j = blockIdx.x * 256 + threadIdx.x;
    f[j] = -__logf(s_f[j] + 1e-7f) * (1.0f / 1.1f);
    s_f[j] = 0.f;
}

__global__ void k_g_row(const float* __restrict__ dis,
                        const float* __restrict__ pd,
                        const float* __restrict__ f,
                        float* __restrict__ g,
                        float* __restrict__ diff_acc,
                        const int* __restrict__ done) {
    if (*done) return;
    const int i = blockIdx.x;
    const float* p = dis + (size_t)i * MM;
    float acc = 0.f;
#pragma unroll 4
    for (int j = threadIdx.x; j < MM; j += 256) {
        float e = __expf(fmaf(p[j], -10.0f, f[j]));
        acc = fmaf(pd[j], e, acc);
    }
    __shared__ float red[256];
    red[threadIdx.x] = acc;
    __syncthreads();
    for (int s = 128; s > 0; s >>= 1) {
        if (threadIdx.x < s) red[threadIdx.x] += red[threadIdx.x + s];
        __syncthreads();
    }
    if (threadIdx.x == 0) {
        float gn = -__logf(red[0] + 1e-7f);
        atomicAdd(diff_acc, fabsf(gn - g[i]));
        g[i] = gn;
    }
}

__global__ void k_check(float* __restrict__ diff_acc, int* __restrict__ done) {
    if (!*done) {
        float diff = 0.1f * (*diff_acc / (float)NN);
        if (diff < 5e-4f) *done = 1;
    }
    *diff_acc = 0.f;
}

// ===========================================================================
extern "C" void kernel_launch(void* const* d_in, const int* in_sizes, int n_in,
                              void* d_out, int out_size, void* d_ws, size_t ws_size,
                              hipStream_t stream) {
    const float* dis = (const float*)d_in[0];   // (NN, MM) fp32
    const float* pd  = (const float*)d_in[1];   // (MM,)
    const float* tm  = (const float*)d_in[2];   // (NN,)
    float* out = (float*)d_out;

    const size_t kBytes = (size_t)NN * MM;      // 32 MiB each (fp8)
    const size_t need   = 2 * kBytes
                        + (size_t)(2 * MM + 2 * NN + 512) * sizeof(float) + 64;

    if (ws_size >= need) {
        unsigned char* K8  = (unsigned char*)d_ws;
        unsigned char* KT8 = (unsigned char*)d_ws + kBytes;
        float* fbuf     = (float*)((char*)d_ws + 2 * kBytes);
        float* vbuf     = fbuf + MM;
        float* gbuf     = vbuf + MM;
        float* wbuf     = gbuf + NN;
        float* diffpart = wbuf + NN;            // 512 floats
        unsigned* counter = (unsigned*)(diffpart + 512);
        int*      done    = (int*)(counter + 1);

        k_prep<<<dim3(MM / 64, NN / 64), 256, 0, stream>>>(dis, K8, KT8,
                                                           tm, gbuf, wbuf,
                                                           counter, done);
        for (int it = 0; it < 100; ++it) {
            k_phaseA<<<1024, 256, 0, stream>>>(KT8, pd, wbuf, fbuf, vbuf, done);
            k_phaseB<<<512, 256, 0, stream>>>(K8, tm, vbuf, gbuf, wbuf,
                                              diffpart, counter, done);
        }
        k_out<<<(MM + NN + 255) / 256, 256, 0, stream>>>(fbuf, gbuf, out);
    } else {
        // ---------------- legacy fallback ----------------
        float* g        = (float*)d_ws;
        float* f        = g + NN;
        float* s_f      = f + MM;
        float* diff_acc = s_f + MM;
        int*   done     = (int*)(diff_acc + 1);

        hipMemsetAsync(d_ws, 0, (size_t)(NN + 2 * MM + 2) * sizeof(float), stream);

        dim3 gridF(MM / 256, 8);
        for (int it = 0; it < 100; ++it) {
            k_f_partial<<<gridF, 256, 0, stream>>>(dis, tm, g, s_f, done);
            k_f_final<<<MM / 256, 256, 0, stream>>>(f, s_f, done);
            k_g_row<<<NN, 256, 0, stream>>>(dis, pd, f, g, diff_acc, done);
            k_check<<<1, 1, 0, stream>>>(diff_acc, done);
        }
        k_out<<<(MM + NN + 255) / 256, 256, 0, stream>>>(f, g, out);
    }
}